// Round 5
// baseline (48.877 us; speedup 1.0000x reference)
//
#include <hip/hip_runtime.h>
#include <stdint.h>

#define N_   64
#define C_   64
#define W_   4096
#define F_   64
#define WW_  9
#define OW_  4088        // W_ - WW_ + 1
#define WBLK 128
#define WROWS 136        // WBLK + 8 halo

typedef __bf16 bf16x8 __attribute__((ext_vector_type(8)));
typedef float  f32x4  __attribute__((ext_vector_type(4)));

__device__ __forceinline__ unsigned short f2bf(float f) {
    union { float f; uint32_t u; } v; v.f = f;
    uint32_t u = v.u;
    return (unsigned short)((u + 0x7FFFu + ((u >> 16) & 1u)) >> 16);  // RNE
}

// filt fp32 [F][C][WW] -> filtB bf16, fragment-major [t][f0h][m][u][lane][8j]
//   f = f0h*32 + u*16 + (lane&15),  c = m*32 + (lane>>4)*8 + j
// Each B-fragment load in the main kernel is ONE contiguous 1KB wave load (L2-resident).
__global__ __launch_bounds__(256) void prep_filt_k(const float* __restrict__ filt,
                                                   unsigned short* __restrict__ filtB) {
    int id = blockIdx.x * 256 + threadIdx.x;
    if (id < WW_ * F_ * C_) {
        int j    = id & 7;
        int lane = (id >> 3) & 63;
        int u    = (id >> 9) & 1;
        int m    = (id >> 10) & 1;
        int f0h  = (id >> 11) & 1;
        int t    = id >> 12;
        int l15  = lane & 15, lg = lane >> 4;
        int f = f0h * 32 + u * 16 + l15;
        int c = m * 32 + lg * 8 + j;
        filtB[id] = f2bf(filt[(f * C_ + c) * WW_ + t]);
    }
}

// One block = one (n, 128-w tile), all 64 filters. 4 waves.
// 8 blocks/CU (VGPR<=64, LDS 17408*8=139KB): TLP covers L2/LDS latency.
__global__ __launch_bounds__(256, 8) void conv_k(const float* __restrict__ x,
                                                 const unsigned short* __restrict__ filtB,
                                                 const float* __restrict__ bias,
                                                 float* __restrict__ out) {
    __shared__ unsigned short xs[WROWS * 64];   // 17408 B, swizzled rows of 128B

    const int tid  = threadIdx.x;
    const int lane = tid & 63;
    const int wv   = tid >> 6;
    const int n    = blockIdx.y;
    const int w0   = blockIdx.x * WBLK;

    // ---- staging: x[c][w0..w0+135] f32 -> xs[w][c] bf16, chunk-XOR swizzled ----
    {
        const int c4 = (wv << 4) + (((tid >> 4) & 3) << 2);
        const int wq = (tid & 15) << 2;
        const int cg = c4 >> 3;
        const int cs = c4 & 7;             // 0 or 4
        const float* xb = x + ((size_t)(n * C_ + c4)) * W_ + w0;
        #pragma unroll
        for (int j = 0; j < 2; ++j) {
            const int wl = wq + j * 64;    // w0+wl+3 <= 4095: in-bounds
            float4 r0 = *reinterpret_cast<const float4*>(xb + 0 * W_ + wl);
            float4 r1 = *reinterpret_cast<const float4*>(xb + 1 * W_ + wl);
            float4 r2 = *reinterpret_cast<const float4*>(xb + 2 * W_ + wl);
            float4 r3 = *reinterpret_cast<const float4*>(xb + 3 * W_ + wl);
            const float* p0 = &r0.x; const float* p1 = &r1.x;
            const float* p2 = &r2.x; const float* p3 = &r3.x;
            #pragma unroll
            for (int jj = 0; jj < 4; ++jj) {
                int w = wl + jj;
                ushort4 u;
                u.x = f2bf(p0[jj]); u.y = f2bf(p1[jj]);
                u.z = f2bf(p2[jj]); u.w = f2bf(p3[jj]);
                *reinterpret_cast<ushort4*>(&xs[w * 64 + ((cg ^ (w & 7)) << 3) + cs]) = u;
            }
        }
        // Halo w = 128..135 (8 w x 64 c), threads 0..31, guarded.
        if (tid < 32) {
            const int hc4 = (tid & 15) << 2;
            const int hwl = 128 + ((tid >> 4) << 2);
            const int hcg = hc4 >> 3;
            const int hcs = hc4 & 7;
            #pragma unroll
            for (int jj = 0; jj < 4; ++jj) {
                int w  = hwl + jj;
                int gw = w0 + w;
                ushort4 u;
                if (gw < W_) {
                    const float* hp = x + ((size_t)(n * C_ + hc4)) * W_ + gw;
                    u.x = f2bf(hp[0]);
                    u.y = f2bf(hp[(size_t)W_]);
                    u.z = f2bf(hp[(size_t)2 * W_]);
                    u.w = f2bf(hp[(size_t)3 * W_]);
                } else {
                    u.x = u.y = u.z = u.w = 0;
                }
                *reinterpret_cast<ushort4*>(&xs[w * 64 + ((hcg ^ (w & 7)) << 3) + hcs]) = u;
            }
        }
    }
    __syncthreads();

    // ---- compute: wave quadrant = 64w x 32f ----
    const int f0h = wv & 1;
    const int whb = (wv >> 1) * 64;
    const int l15 = lane & 15;
    const int lg  = lane >> 4;

    const unsigned short* Bb = filtB + f0h * 2048 + lane * 8;
    const float bv0 = 64.0f * bias[f0h * 32 + l15];        // ref adds bias per channel -> C*bias
    const float bv1 = 64.0f * bias[f0h * 32 + 16 + l15];

    f32x4 acc[4][2];
    #pragma unroll
    for (int s = 0; s < 4; ++s) {
        acc[s][0] = (f32x4){0.f, 0.f, 0.f, 0.f};
        acc[s][1] = (f32x4){0.f, 0.f, 0.f, 0.f};
    }

    #pragma unroll
    for (int t = 0; t < WW_; ++t) {
        #pragma unroll
        for (int m = 0; m < 2; ++m) {
            bf16x8 b0 = *reinterpret_cast<const bf16x8*>(Bb + t * 4096 + m * 1024);
            bf16x8 b1 = *reinterpret_cast<const bf16x8*>(Bb + t * 4096 + m * 1024 + 512);
            #pragma unroll
            for (int s = 0; s < 4; ++s) {
                int row   = whb + s * 16 + l15 + t;              // <= 135
                int chunk = ((m << 2) | lg) ^ (row & 7);
                bf16x8 a  = *reinterpret_cast<const bf16x8*>(&xs[row * 64 + chunk * 8]);
                acc[s][0] = __builtin_amdgcn_mfma_f32_16x16x32_bf16(a, b0, acc[s][0], 0, 0, 0);
                acc[s][1] = __builtin_amdgcn_mfma_f32_16x16x32_bf16(a, b1, acc[s][1], 0, 0, 0);
            }
        }
    }

    // ---- epilogue: D col=f=lane&15, row=w=(lane>>4)*4+reg ; fused bias; float4 stores ----
    const int fb = f0h * 32 + l15;
    #pragma unroll
    for (int s = 0; s < 4; ++s) {
        int wg = w0 + whb + s * 16 + lg * 4;
        if (wg < OW_) {                    // wg%4==0, OW_%4==0 -> whole float4 in-range
            float4 o0, o1;
            o0.x = acc[s][0][0] + bv0; o0.y = acc[s][0][1] + bv0;
            o0.z = acc[s][0][2] + bv0; o0.w = acc[s][0][3] + bv0;
            o1.x = acc[s][1][0] + bv1; o1.y = acc[s][1][1] + bv1;
            o1.z = acc[s][1][2] + bv1; o1.w = acc[s][1][3] + bv1;
            *reinterpret_cast<float4*>(out + ((size_t)(n * F_ + fb) * OW_ + wg))      = o0;
            *reinterpret_cast<float4*>(out + ((size_t)(n * F_ + fb + 16) * OW_ + wg)) = o1;
        }
    }
}

extern "C" void kernel_launch(void* const* d_in, const int* in_sizes, int n_in,
                              void* d_out, int out_size, void* d_ws, size_t ws_size,
                              hipStream_t stream) {
    const float* x    = (const float*)d_in[0];
    const float* filt = (const float*)d_in[1];
    const float* bias = (const float*)d_in[2];
    float* out        = (float*)d_out;

    unsigned short* filtB = (unsigned short*)d_ws;   // 9*64*64 bf16 = 73728 B

    prep_filt_k<<<(WW_ * F_ * C_ + 255) / 256, 256, 0, stream>>>(filt, filtB);

    dim3 grid(W_ / WBLK, N_);   // 32 x 64 = 2048 blocks = 8/CU, fully resident
    conv_k<<<grid, 256, 0, stream>>>(x, filtB, bias, out);
}

// Round 6
// 48.787 us; speedup vs baseline: 1.0018x; 1.0018x over previous
//
#include <hip/hip_runtime.h>
#include <stdint.h>

#define N_   64
#define C_   64
#define W_   4096
#define F_   64
#define WW_  9
#define OW_  4088        // W_ - WW_ + 1
#define WBLK 64          // w-tile per wave
#define WROWS 72         // WBLK + 8 halo

typedef __bf16 bf16x8 __attribute__((ext_vector_type(8)));
typedef float  f32x4  __attribute__((ext_vector_type(4)));

__device__ __forceinline__ unsigned short f2bf(float f) {
    union { float f; uint32_t u; } v; v.f = f;
    uint32_t u = v.u;
    return (unsigned short)((u + 0x7FFFu + ((u >> 16) & 1u)) >> 16);  // RNE
}

// pack 4 floats -> 4 bf16 (two v_cvt_pk_bf16_f32, RNE)
__device__ __forceinline__ uint2 pk4(float a, float b, float c, float d) {
    uint2 r;
    asm volatile("v_cvt_pk_bf16_f32 %0, %1, %2" : "=v"(r.x) : "v"(a), "v"(b));
    asm volatile("v_cvt_pk_bf16_f32 %0, %1, %2" : "=v"(r.y) : "v"(c), "v"(d));
    return r;
}

// filt fp32 [F][C][WW] -> filtB bf16, fragment-major [t][m][u][lane][8j]
//   f = u*16 + (lane&15),  c = m*32 + (lane>>4)*8 + j
// Each B-fragment load in the main kernel is ONE contiguous 1KB wave load (L2-resident).
__global__ __launch_bounds__(256) void prep_filt_k(const float* __restrict__ filt,
                                                   unsigned short* __restrict__ filtB) {
    int id = blockIdx.x * 256 + threadIdx.x;
    if (id < WW_ * F_ * C_) {
        int j    = id & 7;
        int lane = (id >> 3) & 63;
        int uu   = (id >> 9) & 3;
        int m    = (id >> 11) & 1;
        int t    = id >> 12;
        int l15  = lane & 15, lg = lane >> 4;
        int f = uu * 16 + l15;
        int c = m * 32 + lg * 8 + j;
        filtB[id] = f2bf(filt[(f * C_ + c) * WW_ + t]);
    }
}

// One block = ONE WAVE = one (n, 64-w tile) x all 64 filters.
// No __syncthreads anywhere: the wave stages its own LDS tile and consumes it
// (lgkmcnt-only dependency). Resident waves sit at different phases -> natural
// overlap of VMEM / LDS / MFMA pipes across waves.
__global__ __launch_bounds__(64, 3) void conv_k(const float* __restrict__ x,
                                                const unsigned short* __restrict__ filtB,
                                                const float* __restrict__ bias,
                                                float* __restrict__ out) {
    __shared__ unsigned short xs[WROWS * 64];   // 9216 B, swizzled rows of 128B

    const int lane = threadIdx.x;               // 0..63
    const int n    = blockIdx.y;
    const int w0   = blockIdx.x * WBLK;
    const int l15  = lane & 15;
    const int lg   = lane >> 4;

    // ---- stage: x[c][w0..w0+71] f32 -> xs[w][c] bf16, chunk-XOR swizzled ----
    // Main 64 w: lane covers c4 = lg*4 + 16*i (i=0..3), w = l15*4 .. +3.
    // Per load instr: 4 groups x 256B contiguous (fully coalesced).
    {
        const int wq = l15 << 2;
        const int cs = (lg << 2) & 7;           // 0 or 4
        const float* xb = x + ((size_t)(n * C_ + (lg << 2))) * W_ + w0 + wq;
        #pragma unroll
        for (int i = 0; i < 4; ++i) {
            const float* xi = xb + (size_t)(i * 16) * W_;
            float4 r0 = *reinterpret_cast<const float4*>(xi);
            float4 r1 = *reinterpret_cast<const float4*>(xi + W_);
            float4 r2 = *reinterpret_cast<const float4*>(xi + 2 * W_);
            float4 r3 = *reinterpret_cast<const float4*>(xi + 3 * W_);
            const int cg = (lg >> 1) + (i << 1);   // (c4>>3)
            const float* p0 = &r0.x; const float* p1 = &r1.x;
            const float* p2 = &r2.x; const float* p3 = &r3.x;
            #pragma unroll
            for (int jj = 0; jj < 4; ++jj) {
                int w = wq + jj;
                uint2 u2 = pk4(p0[jj], p1[jj], p2[jj], p3[jj]);
                *reinterpret_cast<uint2*>(&xs[w * 64 + ((cg ^ (w & 7)) << 3) + cs]) = u2;
            }
        }
        // Halo w = 64..71 (8 w x 64 c): lanes 0..31, guarded (last tile crosses W).
        if (lane < 32) {
            const int hc4 = (lane >> 1) << 2;   // 0..60
            const int hw  = 64 + ((lane & 1) << 2);
            const int hcg = hc4 >> 3;
            const int hcs = hc4 & 7;
            const float* hp = x + ((size_t)(n * C_ + hc4)) * W_ + w0 + hw;
            #pragma unroll
            for (int jj = 0; jj < 4; ++jj) {
                int w  = hw + jj;
                int gw = w0 + w;
                float a0 = 0.f, a1 = 0.f, a2 = 0.f, a3 = 0.f;
                if (gw < W_) {
                    a0 = hp[jj];
                    a1 = hp[jj + (size_t)W_];
                    a2 = hp[jj + (size_t)2 * W_];
                    a3 = hp[jj + (size_t)3 * W_];
                }
                uint2 u2 = pk4(a0, a1, a2, a3);
                *reinterpret_cast<uint2*>(&xs[w * 64 + ((hcg ^ (w & 7)) << 3) + hcs]) = u2;
            }
        }
    }
    // no barrier: single wave, compiler inserts lgkmcnt for RAW on xs

    // ---- compute: 64w x 64f per wave; K = 9 taps x 64 c ----
    const unsigned short* Bb = filtB + lane * 8;

    float bv[4];
    #pragma unroll
    for (int uu = 0; uu < 4; ++uu)
        bv[uu] = 64.0f * bias[uu * 16 + l15];   // ref adds bias once per channel -> C*bias

    f32x4 acc[4][4];                            // [s(w)][u(f)]
    #pragma unroll
    for (int s = 0; s < 4; ++s)
        #pragma unroll
        for (int uu = 0; uu < 4; ++uu)
            acc[s][uu] = (f32x4){0.f, 0.f, 0.f, 0.f};

    #pragma unroll
    for (int t = 0; t < WW_; ++t) {
        #pragma unroll
        for (int m = 0; m < 2; ++m) {
            // A frags: 4 w-rows from LDS
            bf16x8 a[4];
            #pragma unroll
            for (int s = 0; s < 4; ++s) {
                int row   = s * 16 + l15 + t;                    // <= 71
                int chunk = ((m << 2) | lg) ^ (row & 7);
                a[s] = *reinterpret_cast<const bf16x8*>(&xs[row * 64 + chunk * 8]);
            }
            // B frags: 4 f-quarters, each one coalesced 1KB wave load (L2)
            bf16x8 b[4];
            #pragma unroll
            for (int uu = 0; uu < 4; ++uu)
                b[uu] = *reinterpret_cast<const bf16x8*>(Bb + (((t * 2 + m) * 4 + uu) << 9));
            __builtin_amdgcn_s_setprio(1);
            #pragma unroll
            for (int s = 0; s < 4; ++s)
                #pragma unroll
                for (int uu = 0; uu < 4; ++uu)
                    acc[s][uu] = __builtin_amdgcn_mfma_f32_16x16x32_bf16(a[s], b[uu], acc[s][uu], 0, 0, 0);
            __builtin_amdgcn_s_setprio(0);
        }
    }

    // ---- epilogue: D col=f=lane&15, row=w=(lane>>4)*4+reg ; fused bias; float4 stores ----
    #pragma unroll
    for (int uu = 0; uu < 4; ++uu) {
        const int f = uu * 16 + l15;
        #pragma unroll
        for (int s = 0; s < 4; ++s) {
            int wg = w0 + s * 16 + lg * 4;
            if (wg < OW_) {                    // wg%4==0, OW_%4==0 -> whole float4 in-range
                float4 o;
                o.x = acc[s][uu][0] + bv[uu];
                o.y = acc[s][uu][1] + bv[uu];
                o.z = acc[s][uu][2] + bv[uu];
                o.w = acc[s][uu][3] + bv[uu];
                *reinterpret_cast<float4*>(out + ((size_t)(n * F_ + f) * OW_ + wg)) = o;
            }
        }
    }
}

extern "C" void kernel_launch(void* const* d_in, const int* in_sizes, int n_in,
                              void* d_out, int out_size, void* d_ws, size_t ws_size,
                              hipStream_t stream) {
    const float* x    = (const float*)d_in[0];
    const float* filt = (const float*)d_in[1];
    const float* bias = (const float*)d_in[2];
    float* out        = (float*)d_out;

    unsigned short* filtB = (unsigned short*)d_ws;   // 9*64*64 bf16 = 73728 B

    prep_filt_k<<<(WW_ * F_ * C_ + 255) / 256, 256, 0, stream>>>(filt, filtB);

    dim3 grid(W_ / WBLK, N_);   // 64 x 64 = 4096 one-wave blocks
    conv_k<<<grid, 64, 0, stream>>>(x, filtB, bias, out);
}

// Round 7
// 44.118 us; speedup vs baseline: 1.1079x; 1.1058x over previous
//
#include <hip/hip_runtime.h>
#include <stdint.h>

#define N_   64
#define C_   64
#define W_   4096
#define F_   64
#define WW_  9
#define OW_  4088        // W_ - WW_ + 1
#define WBLK 128
#define WROWS 136        // WBLK + 8 halo

typedef __bf16 bf16x8 __attribute__((ext_vector_type(8)));
typedef float  f32x4  __attribute__((ext_vector_type(4)));

__device__ __forceinline__ unsigned short f2bf(float f) {
    union { float f; uint32_t u; } v; v.f = f;
    uint32_t u = v.u;
    return (unsigned short)((u + 0x7FFFu + ((u >> 16) & 1u)) >> 16);  // RNE
}

// pack 4 floats -> 4 bf16 (two v_cvt_pk_bf16_f32, RNE); low half = first operand
__device__ __forceinline__ uint2 pk4(float a, float b, float c, float d) {
    uint2 r;
    asm volatile("v_cvt_pk_bf16_f32 %0, %1, %2" : "=v"(r.x) : "v"(a), "v"(b));
    asm volatile("v_cvt_pk_bf16_f32 %0, %1, %2" : "=v"(r.y) : "v"(c), "v"(d));
    return r;
}

// filt fp32 [F][C][WW] -> filtB bf16, fragment-major [t][f0h][m][u][lane][8j]
//   f = f0h*32 + u*16 + (lane&15),  c = m*32 + (lane>>4)*8 + j
// Each B-fragment load in the main kernel is ONE contiguous 1KB wave load (L2-resident).
__global__ __launch_bounds__(256) void prep_filt_k(const float* __restrict__ filt,
                                                   unsigned short* __restrict__ filtB) {
    int id = blockIdx.x * 256 + threadIdx.x;
    if (id < WW_ * F_ * C_) {
        int j    = id & 7;
        int lane = (id >> 3) & 63;
        int u    = (id >> 9) & 1;
        int m    = (id >> 10) & 1;
        int f0h  = (id >> 11) & 1;
        int t    = id >> 12;
        int l15  = lane & 15, lg = lane >> 4;
        int f = f0h * 32 + u * 16 + l15;
        int c = m * 32 + lg * 8 + j;
        filtB[id] = f2bf(filt[(f * C_ + c) * WW_ + t]);
    }
}

// One block = one (n, 128-w tile), all 64 filters. 4 waves.
// (256,6): 6 blocks/CU (LDS 6*17408=104KB, VGPR cap ~85 >> 48 needed -> no spill).
// 24 waves/CU of cross-block phase diversity covers L2/LDS latency.
__global__ __launch_bounds__(256, 6) void conv_k(const float* __restrict__ x,
                                                 const unsigned short* __restrict__ filtB,
                                                 const float* __restrict__ bias,
                                                 float* __restrict__ out) {
    __shared__ unsigned short xs[WROWS * 64];   // 17408 B, swizzled rows of 128B

    const int tid  = threadIdx.x;
    const int lane = tid & 63;
    const int wv   = tid >> 6;
    const int n    = blockIdx.y;
    const int w0   = blockIdx.x * WBLK;

    // ---- staging: x[c][w0..w0+135] f32 -> xs[w][c] bf16, chunk-XOR swizzled ----
    {
        const int c4 = (wv << 4) + (((tid >> 4) & 3) << 2);
        const int wq = (tid & 15) << 2;
        const int cg = c4 >> 3;
        const int cs = c4 & 7;             // 0 or 4
        const float* xb = x + ((size_t)(n * C_ + c4)) * W_ + w0;
        #pragma unroll
        for (int j = 0; j < 2; ++j) {
            const int wl = wq + j * 64;    // w0+wl+3 <= 4095: in-bounds
            float4 r0 = *reinterpret_cast<const float4*>(xb + 0 * W_ + wl);
            float4 r1 = *reinterpret_cast<const float4*>(xb + 1 * W_ + wl);
            float4 r2 = *reinterpret_cast<const float4*>(xb + 2 * W_ + wl);
            float4 r3 = *reinterpret_cast<const float4*>(xb + 3 * W_ + wl);
            const float* p0 = &r0.x; const float* p1 = &r1.x;
            const float* p2 = &r2.x; const float* p3 = &r3.x;
            #pragma unroll
            for (int jj = 0; jj < 4; ++jj) {
                int w = wl + jj;
                uint2 u2 = pk4(p0[jj], p1[jj], p2[jj], p3[jj]);
                *reinterpret_cast<uint2*>(&xs[w * 64 + ((cg ^ (w & 7)) << 3) + cs]) = u2;
            }
        }
        // Halo w = 128..135 (8 w x 64 c), threads 0..31, guarded.
        if (tid < 32) {
            const int hc4 = (tid & 15) << 2;
            const int hwl = 128 + ((tid >> 4) << 2);
            const int hcg = hc4 >> 3;
            const int hcs = hc4 & 7;
            #pragma unroll
            for (int jj = 0; jj < 4; ++jj) {
                int w  = hwl + jj;
                int gw = w0 + w;
                float a0 = 0.f, a1 = 0.f, a2 = 0.f, a3 = 0.f;
                if (gw < W_) {
                    const float* hp = x + ((size_t)(n * C_ + hc4)) * W_ + gw;
                    a0 = hp[0];
                    a1 = hp[(size_t)W_];
                    a2 = hp[(size_t)2 * W_];
                    a3 = hp[(size_t)3 * W_];
                }
                uint2 u2 = pk4(a0, a1, a2, a3);
                *reinterpret_cast<uint2*>(&xs[w * 64 + ((hcg ^ (w & 7)) << 3) + hcs]) = u2;
            }
        }
    }
    __syncthreads();

    // ---- compute: wave quadrant = 64w x 32f ----
    const int f0h = wv & 1;
    const int whb = (wv >> 1) * 64;
    const int l15 = lane & 15;
    const int lg  = lane >> 4;

    const unsigned short* Bb = filtB + f0h * 2048 + lane * 8;
    const float bv0 = 64.0f * bias[f0h * 32 + l15];        // ref adds bias per channel -> C*bias
    const float bv1 = 64.0f * bias[f0h * 32 + 16 + l15];

    f32x4 acc[4][2];
    #pragma unroll
    for (int s = 0; s < 4; ++s) {
        acc[s][0] = (f32x4){0.f, 0.f, 0.f, 0.f};
        acc[s][1] = (f32x4){0.f, 0.f, 0.f, 0.f};
    }

    #pragma unroll
    for (int t = 0; t < WW_; ++t) {
        #pragma unroll
        for (int m = 0; m < 2; ++m) {
            bf16x8 b0 = *reinterpret_cast<const bf16x8*>(Bb + t * 4096 + m * 1024);
            bf16x8 b1 = *reinterpret_cast<const bf16x8*>(Bb + t * 4096 + m * 1024 + 512);
            #pragma unroll
            for (int s = 0; s < 4; ++s) {
                int row   = whb + s * 16 + l15 + t;              // <= 135
                int chunk = ((m << 2) | lg) ^ (row & 7);
                bf16x8 a  = *reinterpret_cast<const bf16x8*>(&xs[row * 64 + chunk * 8]);
                acc[s][0] = __builtin_amdgcn_mfma_f32_16x16x32_bf16(a, b0, acc[s][0], 0, 0, 0);
                acc[s][1] = __builtin_amdgcn_mfma_f32_16x16x32_bf16(a, b1, acc[s][1], 0, 0, 0);
            }
        }
    }

    // ---- epilogue: D col=f=lane&15, row=w=(lane>>4)*4+reg ; fused bias; float4 stores ----
    const int fb = f0h * 32 + l15;
    #pragma unroll
    for (int s = 0; s < 4; ++s) {
        int wg = w0 + whb + s * 16 + lg * 4;
        if (wg < OW_) {                    // wg%4==0, OW_%4==0 -> whole float4 in-range
            float4 o0, o1;
            o0.x = acc[s][0][0] + bv0; o0.y = acc[s][0][1] + bv0;
            o0.z = acc[s][0][2] + bv0; o0.w = acc[s][0][3] + bv0;
            o1.x = acc[s][1][0] + bv1; o1.y = acc[s][1][1] + bv1;
            o1.z = acc[s][1][2] + bv1; o1.w = acc[s][1][3] + bv1;
            *reinterpret_cast<float4*>(out + ((size_t)(n * F_ + fb) * OW_ + wg))      = o0;
            *reinterpret_cast<float4*>(out + ((size_t)(n * F_ + fb + 16) * OW_ + wg)) = o1;
        }
    }
}

extern "C" void kernel_launch(void* const* d_in, const int* in_sizes, int n_in,
                              void* d_out, int out_size, void* d_ws, size_t ws_size,
                              hipStream_t stream) {
    const float* x    = (const float*)d_in[0];
    const float* filt = (const float*)d_in[1];
    const float* bias = (const float*)d_in[2];
    float* out        = (float*)d_out;

    unsigned short* filtB = (unsigned short*)d_ws;   // 9*64*64 bf16 = 73728 B

    prep_filt_k<<<(WW_ * F_ * C_ + 255) / 256, 256, 0, stream>>>(filt, filtB);

    dim3 grid(W_ / WBLK, N_);   // 32 x 64 = 2048 blocks, 6/CU resident
    conv_k<<<grid, 256, 0, stream>>>(x, filtB, bias, out);
}